// Round 2
// baseline (454.697 us; speedup 1.0000x reference)
//
#include <hip/hip_runtime.h>
#include <hip/hip_bf16.h>
#include <stdint.h>

#define NN 4096
#define NITER 10
#define NCHUNK 128
#define RPC (NN / NCHUNK)   // rows per chunk in column pass = 32

__device__ __forceinline__ float bf2f(unsigned short u) {
  union { unsigned int i; float f; } x; x.i = ((unsigned int)u) << 16; return x.f;
}
__device__ __forceinline__ unsigned short f2bf(float f) {
  union { float f; unsigned int i; } x; x.f = f;
  unsigned int i = x.i;
  i += 0x7FFFu + ((i >> 16) & 1u);   // round-to-nearest-even
  return (unsigned short)(i >> 16);
}
// unpack 2 bf16 packed in a u32 (little-endian: low ushort = element 0)
__device__ __forceinline__ float2 unpk(unsigned int u) {
  union { unsigned int i; float f; } a, b;
  a.i = u << 16; b.i = u & 0xFFFF0000u;
  return make_float2(a.f, b.f);
}
// eps scalar: tolerate either f32 or bf16 storage (f32 expected)
__device__ __forceinline__ float read_eps(const void* p) {
  float f = *(const float*)p;
  if (f > 1e-4f && f < 1.0f) return f;
  return bf2f(*(const unsigned short*)p);
}

// ---------------------------------------------------------------------------
// K[i] = exp(-C[i]/eps) stored bf16; also init v_t[m][s] = 1
// grid: 8192 blocks x 256, 8 f32 in -> 8 bf16 out per thread
__global__ __launch_bounds__(256) void build_k(
    const float* __restrict__ C, const void* __restrict__ epsp,
    unsigned short* __restrict__ K, float* __restrict__ v_t) {
  int gid = blockIdx.x * 256 + threadIdx.x;
  float nie = -1.0f / read_eps(epsp);
  float4 c0 = ((const float4*)C)[gid * 2];
  float4 c1 = ((const float4*)C)[gid * 2 + 1];
  float e[8];
  e[0] = __expf(c0.x * nie); e[1] = __expf(c0.y * nie);
  e[2] = __expf(c0.z * nie); e[3] = __expf(c0.w * nie);
  e[4] = __expf(c1.x * nie); e[5] = __expf(c1.y * nie);
  e[6] = __expf(c1.z * nie); e[7] = __expf(c1.w * nie);
  uint4 o;
  o.x = (unsigned int)f2bf(e[0]) | ((unsigned int)f2bf(e[1]) << 16);
  o.y = (unsigned int)f2bf(e[2]) | ((unsigned int)f2bf(e[3]) << 16);
  o.z = (unsigned int)f2bf(e[4]) | ((unsigned int)f2bf(e[5]) << 16);
  o.w = (unsigned int)f2bf(e[6]) | ((unsigned int)f2bf(e[7]) << 16);
  ((uint4*)K)[gid] = o;
  if (gid < NN) ((float4*)v_t)[gid] = make_float4(1.f, 1.f, 1.f, 1.f);
}

// ---------------------------------------------------------------------------
// f-update: u_t[n][s] = alpha[s][n] / sum_m K[n][m] * v_t[m][s]
// 1 wave handles 2 rows; block=256 (4 waves) -> 8 rows/block; grid 512 blocks
__global__ __launch_bounds__(256) void f_update(
    const unsigned short* __restrict__ K, const float* __restrict__ v_t,
    const float* __restrict__ alpha, float* __restrict__ u_t) {
  int wave = threadIdx.x >> 6, lane = threadIdx.x & 63;
  int row0 = (blockIdx.x * 4 + wave) * 2;
  const uint4* K0 = (const uint4*)(K + (size_t)row0 * NN);
  const uint4* K1 = (const uint4*)(K + (size_t)(row0 + 1) * NN);
  const float4* V = (const float4*)v_t;
  float acc[2][4] = {};
#pragma unroll
  for (int i = 0; i < 8; ++i) {
    int m = i * 512 + lane * 8;   // this lane's first element this iter
    uint4 k0 = K0[m >> 3];
    uint4 k1 = K1[m >> 3];
    float4 vv[8];
#pragma unroll
    for (int j = 0; j < 8; ++j) vv[j] = V[m + j];
    unsigned int kw0[4] = {k0.x, k0.y, k0.z, k0.w};
    unsigned int kw1[4] = {k1.x, k1.y, k1.z, k1.w};
#pragma unroll
    for (int j = 0; j < 4; ++j) {
      float2 a = unpk(kw0[j]);
      float2 b = unpk(kw1[j]);
      float4 v0 = vv[2 * j], v1 = vv[2 * j + 1];
      acc[0][0] += a.x * v0.x; acc[0][1] += a.x * v0.y; acc[0][2] += a.x * v0.z; acc[0][3] += a.x * v0.w;
      acc[0][0] += a.y * v1.x; acc[0][1] += a.y * v1.y; acc[0][2] += a.y * v1.z; acc[0][3] += a.y * v1.w;
      acc[1][0] += b.x * v0.x; acc[1][1] += b.x * v0.y; acc[1][2] += b.x * v0.z; acc[1][3] += b.x * v0.w;
      acc[1][0] += b.y * v1.x; acc[1][1] += b.y * v1.y; acc[1][2] += b.y * v1.z; acc[1][3] += b.y * v1.w;
    }
  }
#pragma unroll
  for (int off = 32; off > 0; off >>= 1)
#pragma unroll
    for (int r = 0; r < 2; ++r)
#pragma unroll
      for (int s = 0; s < 4; ++s)
        acc[r][s] += __shfl_xor(acc[r][s], off);
  if (lane < 2) {
    int row = row0 + lane;
    float r0 = lane ? acc[1][0] : acc[0][0];
    float r1 = lane ? acc[1][1] : acc[0][1];
    float r2 = lane ? acc[1][2] : acc[0][2];
    float r3 = lane ? acc[1][3] : acc[0][3];
    float4 res;
    res.x = alpha[0 * NN + row] / r0;
    res.y = alpha[1 * NN + row] / r1;
    res.z = alpha[2 * NN + row] / r2;
    res.w = alpha[3 * NN + row] / r3;
    ((float4*)u_t)[row] = res;
  }
}

// ---------------------------------------------------------------------------
// g-update phase 1: partial[c][m][s] = sum_{n in chunk c} K[n][m] * u_t[n][s]
// grid: 2 m-tiles x NCHUNK chunks = 256 blocks x 256 thr; thread owns 8 cols
__global__ __launch_bounds__(256) void g_partial(
    const unsigned short* __restrict__ K, const float* __restrict__ u_t,
    float* __restrict__ partial) {
  int mtile = blockIdx.x & 1;
  int c = blockIdx.x >> 1;
  int m0 = mtile * 2048 + threadIdx.x * 8;
  float acc[8][4] = {};
  int nbase = c * RPC;
#pragma unroll 4
  for (int nn = 0; nn < RPC; ++nn) {
    int n = nbase + nn;
    float4 u4 = ((const float4*)u_t)[n];          // wave-uniform
    uint4 k = ((const uint4*)(K + (size_t)n * NN))[m0 >> 3];
    unsigned int kw[4] = {k.x, k.y, k.z, k.w};
#pragma unroll
    for (int j = 0; j < 4; ++j) {
      float2 f = unpk(kw[j]);
      acc[2*j][0]   += f.x * u4.x; acc[2*j][1]   += f.x * u4.y; acc[2*j][2]   += f.x * u4.z; acc[2*j][3]   += f.x * u4.w;
      acc[2*j+1][0] += f.y * u4.x; acc[2*j+1][1] += f.y * u4.y; acc[2*j+1][2] += f.y * u4.z; acc[2*j+1][3] += f.y * u4.w;
    }
  }
  float4* P = (float4*)(partial + ((size_t)c * NN + m0) * 4);
#pragma unroll
  for (int j = 0; j < 8; ++j)
    P[j] = make_float4(acc[j][0], acc[j][1], acc[j][2], acc[j][3]);
}

// ---------------------------------------------------------------------------
// g-update phase 2: v_t[m][s] = beta[s][m] / sum_c partial[c][m][s]
// grid 64 blocks x 64 threads (one thread per column m)
__global__ __launch_bounds__(64) void g_reduce(
    const float* __restrict__ partial, const float* __restrict__ beta,
    float* __restrict__ v_t) {
  int m = blockIdx.x * 64 + threadIdx.x;
  float4 acc = make_float4(0.f, 0.f, 0.f, 0.f);
#pragma unroll 8
  for (int c = 0; c < NCHUNK; ++c) {
    float4 p = ((const float4*)partial)[(size_t)c * NN + m];
    acc.x += p.x; acc.y += p.y; acc.z += p.z; acc.w += p.w;
  }
  float4 res;
  res.x = beta[0 * NN + m] / acc.x;
  res.y = beta[1 * NN + m] / acc.y;
  res.z = beta[2 * NN + m] / acc.z;
  res.w = beta[3 * NN + m] / acc.w;
  ((float4*)v_t)[m] = res;
}

// ---------------------------------------------------------------------------
// out: f[s][n] = eps*log(u[n][s]); g[s][m] = eps*log(v[m][s])  (f32)
// grid 32 blocks x 256 (gid 0..4095 -> f, 4096..8191 -> g)
__global__ __launch_bounds__(256) void finalize(
    const float* __restrict__ u_t, const float* __restrict__ v_t,
    const void* __restrict__ epsp, float* __restrict__ out) {
  int gid = blockIdx.x * 256 + threadIdx.x;
  float eps = read_eps(epsp);
  if (gid < NN) {
    float4 u = ((const float4*)u_t)[gid];
    out[0 * NN + gid] = eps * __logf(u.x);
    out[1 * NN + gid] = eps * __logf(u.y);
    out[2 * NN + gid] = eps * __logf(u.z);
    out[3 * NN + gid] = eps * __logf(u.w);
  } else {
    int m = gid - NN;
    float4 v = ((const float4*)v_t)[m];
    out[4 * NN + 0 * NN + m] = eps * __logf(v.x);
    out[4 * NN + 1 * NN + m] = eps * __logf(v.y);
    out[4 * NN + 2 * NN + m] = eps * __logf(v.z);
    out[4 * NN + 3 * NN + m] = eps * __logf(v.w);
  }
}

// ---------------------------------------------------------------------------
extern "C" void kernel_launch(void* const* d_in, const int* in_sizes, int n_in,
                              void* d_out, int out_size, void* d_ws, size_t ws_size,
                              hipStream_t stream) {
  (void)in_sizes; (void)n_in; (void)out_size; (void)ws_size;
  const float* alpha = (const float*)d_in[0];   // f32 (4,4096)
  const float* beta  = (const float*)d_in[1];   // f32 (4,4096)
  const float* C     = (const float*)d_in[2];   // f32 (4096,4096)
  const void*  epsp  = d_in[3];                 // f32 scalar

  char* ws = (char*)d_ws;
  unsigned short* K  = (unsigned short*)ws;                      // 32 MiB
  float* partial     = (float*)(ws + 33554432);                  // 8 MiB
  float* u_t         = (float*)(ws + 33554432 + 8388608);        // 64 KiB
  float* v_t         = (float*)(ws + 33554432 + 8388608 + 65536);// 64 KiB
  float* out = (float*)d_out;

  build_k<<<(NN * NN / 8) / 256, 256, 0, stream>>>(C, epsp, K, v_t);
  for (int it = 0; it < NITER; ++it) {
    f_update<<<512, 256, 0, stream>>>(K, v_t, alpha, u_t);
    g_partial<<<2 * NCHUNK, 256, 0, stream>>>(K, u_t, partial);
    g_reduce<<<NN / 64, 64, 0, stream>>>(partial, beta, v_t);
  }
  finalize<<<2 * NN / 256, 256, 0, stream>>>(u_t, v_t, epsp, out);
}